// Round 5
// baseline (181.453 us; speedup 1.0000x reference)
//
#include <hip/hip_runtime.h>
#include <hip/hip_bf16.h>

#define N_NODES 50000
#define N_EDGES 300000
#define N_CLUSTERS 100
#define CH 256      // IN_C == OUT_C == 256
#define CAP 32      // per-node in-edge capacity; P(deg>=32 | lambda~5.4) ~ 1e-13/node

typedef __attribute__((ext_vector_type(8))) short short8;   // bf16x8 MFMA operand (4 VGPRs)
typedef __attribute__((ext_vector_type(4))) float f32x4;    // MFMA accumulator

// float -> bf16 (RNE) bits
static __device__ inline unsigned short f2bf(float f) {
    unsigned int u = __float_as_uint(f);
    u += 0x7fffu + ((u >> 16) & 1u);
    return (unsigned short)(u >> 16);
}

// ---------------- graph preprocessing ----------------

__global__ void init_kernel(int* __restrict__ indeg, int* __restrict__ flags) {
    int i = blockIdx.x * blockDim.x + threadIdx.x;
    if (i < N_NODES) indeg[i] = 0;
    if (i < N_CLUSTERS) flags[i] = 0;
}

// count + bucket-scatter fused: fixed-capacity buckets, no scan
__global__ void scatter_kernel(const int* __restrict__ ei, const int* __restrict__ assign,
                               int* __restrict__ indeg, int* __restrict__ flags,
                               int* __restrict__ csr) {
    int e = blockIdx.x * blockDim.x + threadIdx.x;
    if (e >= N_EDGES) return;
    int s = ei[e], d = ei[N_EDGES + e];
    int cs = assign[s];
    if (cs == assign[d]) {
        int p = atomicAdd(&indeg[d], 1);
        if (p < CAP) csr[d * CAP + p] = s;
        flags[cs] = 1;   // benign race
    }
}

// W (256x256 f32, [k][n]) -> Wt (bf16, [n][k]). block = n, thread = k.
__global__ void convw_kernel(const float* __restrict__ W, unsigned short* __restrict__ Wt) {
    int n = blockIdx.x, k = threadIdx.x;
    Wt[n * CH + k] = f2bf(W[k * CH + n]);
}

// ---------------- xW = X @ W via bf16 MFMA ----------------
// BM=128, BN=256 (full width): each A-tile fetched from HBM exactly once.
// 4 waves; wave owns 64 cols x 128 rows (2 m-subtiles of 64).

#define BM 128
#define BK 32
#define LDSS 40   // LDS row stride in bf16: 80B (16B-aligned, 2-way bank phase = free)

__global__ __launch_bounds__(256, 2) void gemm_bf16(const float* __restrict__ X,
                                                    const unsigned short* __restrict__ Wt,
                                                    unsigned short* __restrict__ xWb) {
    __shared__ unsigned short Xs[BM * LDSS];    // 10.2 KB
    __shared__ unsigned short Ws[CH * LDSS];    // 20.5 KB
    int tid = threadIdx.x;
    int row0 = blockIdx.x * BM;
    int wid = tid >> 6, lane = tid & 63;
    int wn = wid * 64;                          // wave's 64-col slice of 256
    int l15 = lane & 15, quad = lane >> 4;

    f32x4 acc[2][4][4] = {};                    // [h(m-subtile)][mi][ni]

    // A staging: thread t -> row t>>1, k-chunk (t&1)*16 (16 fp32 -> bf16)
    int srow = tid >> 1;
    int skc  = (tid & 1) * 16;
    int garow = row0 + srow; if (garow >= N_NODES) garow = N_NODES - 1;  // clamp, stores guarded
    const float* gA = X + (size_t)garow * CH + skc;
    unsigned short* lA = &Xs[srow * LDSS + skc];
    // B staging: thread t -> row t (all 32 k), bf16
    const unsigned short* gB = Wt + (size_t)tid * CH;
    unsigned short* lB = &Ws[tid * LDSS];

    for (int k0 = 0; k0 < CH; k0 += BK) {
        float4 x0 = *reinterpret_cast<const float4*>(gA + k0);
        float4 x1 = *reinterpret_cast<const float4*>(gA + k0 + 4);
        float4 x2 = *reinterpret_cast<const float4*>(gA + k0 + 8);
        float4 x3 = *reinterpret_cast<const float4*>(gA + k0 + 12);
        uint4 b0 = *reinterpret_cast<const uint4*>(gB + k0);
        uint4 b1 = *reinterpret_cast<const uint4*>(gB + k0 + 8);
        uint4 b2 = *reinterpret_cast<const uint4*>(gB + k0 + 16);
        uint4 b3 = *reinterpret_cast<const uint4*>(gB + k0 + 24);
        ushort4 a0 = { f2bf(x0.x), f2bf(x0.y), f2bf(x0.z), f2bf(x0.w) };
        ushort4 a1 = { f2bf(x1.x), f2bf(x1.y), f2bf(x1.z), f2bf(x1.w) };
        ushort4 a2 = { f2bf(x2.x), f2bf(x2.y), f2bf(x2.z), f2bf(x2.w) };
        ushort4 a3 = { f2bf(x3.x), f2bf(x3.y), f2bf(x3.z), f2bf(x3.w) };
        *reinterpret_cast<ushort4*>(lA)      = a0;
        *reinterpret_cast<ushort4*>(lA + 4)  = a1;
        *reinterpret_cast<ushort4*>(lA + 8)  = a2;
        *reinterpret_cast<ushort4*>(lA + 12) = a3;
        *reinterpret_cast<uint4*>(lB)      = b0;
        *reinterpret_cast<uint4*>(lB + 8)  = b1;
        *reinterpret_cast<uint4*>(lB + 16) = b2;
        *reinterpret_cast<uint4*>(lB + 24) = b3;
        __syncthreads();

        short8 af[2][4], bf[4];
#pragma unroll
        for (int h = 0; h < 2; ++h)
#pragma unroll
            for (int mi = 0; mi < 4; ++mi)
                af[h][mi] = *reinterpret_cast<const short8*>(
                    &Xs[(h * 64 + mi * 16 + l15) * LDSS + quad * 8]);
#pragma unroll
        for (int ni = 0; ni < 4; ++ni)
            bf[ni] = *reinterpret_cast<const short8*>(
                &Ws[(wn + ni * 16 + l15) * LDSS + quad * 8]);
#pragma unroll
        for (int h = 0; h < 2; ++h)
#pragma unroll
            for (int mi = 0; mi < 4; ++mi)
#pragma unroll
                for (int ni = 0; ni < 4; ++ni)
                    acc[h][mi][ni] = __builtin_amdgcn_mfma_f32_16x16x32_bf16(
                        af[h][mi], bf[ni], acc[h][mi][ni], 0, 0, 0);
        __syncthreads();
    }

    // C/D layout: col = lane&15, row = quad*4 + reg  [m89-verified]
#pragma unroll
    for (int h = 0; h < 2; ++h)
#pragma unroll
        for (int mi = 0; mi < 4; ++mi)
#pragma unroll
            for (int r = 0; r < 4; ++r) {
                int grow = row0 + h * 64 + mi * 16 + quad * 4 + r;
                if (grow < N_NODES) {
                    size_t rb = (size_t)grow * CH + wn + l15;
#pragma unroll
                    for (int ni = 0; ni < 4; ++ni)
                        xWb[rb + ni * 16] = f2bf(acc[h][mi][ni][r]);
                }
            }
}

// ---------------- aggregation: parallel edge fetch + shfl broadcast + 4-deep load ILP ----------------
// XCD-aware swizzle: each XCD owns a contiguous 1/8 of nodes so a cluster's
// xWb working set (~256 KB) stays in ONE per-XCD L2.

#define NBLK ((N_NODES + 3) / 4)            // 12500
#define BLK_PER_XCD ((NBLK + 7) / 8)        // 1563

static __device__ inline void bf4_fma(float w, uint2 v, float& ax, float& ay, float& az, float& aw) {
    ax += w * __uint_as_float(v.x << 16);
    ay += w * __uint_as_float(v.x & 0xffff0000u);
    az += w * __uint_as_float(v.y << 16);
    aw += w * __uint_as_float(v.y & 0xffff0000u);
}

__global__ __launch_bounds__(256) void gather_kernel(const unsigned short* __restrict__ xWb,
        const float* __restrict__ X, const float* __restrict__ b,
        const int* __restrict__ assign, const int* __restrict__ flags,
        const int* __restrict__ indeg, const int* __restrict__ csr,
        float* __restrict__ out) {
    int blk = (blockIdx.x & 7) * BLK_PER_XCD + (blockIdx.x >> 3);
    if (blk >= NBLK) return;
    int node = blk * 4 + (threadIdx.x >> 6);
    int lane = threadIdx.x & 63;
    if (node >= N_NODES) return;
    float4* out4 = reinterpret_cast<float4*>(out);
    size_t base4 = (size_t)node * 64 + lane;        // float4 index
    if (flags[assign[node]] == 0) {
        out4[base4] = reinterpret_cast<const float4*>(X)[base4];
        return;
    }
    int cnt_raw = indeg[node];
    int cnt = cnt_raw > CAP ? CAP : cnt_raw;
    float dn = rsqrtf(1.0f + (float)cnt_raw);

    // phase 1: lanes 0..cnt-1 fetch edge index + weight in parallel
    int   s_l = 0;
    float w_l = 0.0f;
    if (lane < cnt) {
        s_l = csr[node * CAP + lane];
        w_l = rsqrtf(1.0f + (float)indeg[s_l]) * dn;
    }

    // self term: norm = 1/deg
    float selfw = dn * dn;
    uint2 sv = *reinterpret_cast<const uint2*>(xWb + (size_t)node * CH + lane * 4);
    float ax = 0, ay = 0, az = 0, aw = 0;
    bf4_fma(selfw, sv, ax, ay, az, aw);

    // phase 2: shfl-broadcast (s,w), gather rows 4 at a time (4 loads in flight)
    int i = 0;
    for (; i + 4 <= cnt; i += 4) {
        int   s0 = __shfl(s_l, i),     s1 = __shfl(s_l, i + 1);
        int   s2 = __shfl(s_l, i + 2), s3 = __shfl(s_l, i + 3);
        float w0 = __shfl(w_l, i),     w1 = __shfl(w_l, i + 1);
        float w2 = __shfl(w_l, i + 2), w3 = __shfl(w_l, i + 3);
        uint2 v0 = *reinterpret_cast<const uint2*>(xWb + (size_t)s0 * CH + lane * 4);
        uint2 v1 = *reinterpret_cast<const uint2*>(xWb + (size_t)s1 * CH + lane * 4);
        uint2 v2 = *reinterpret_cast<const uint2*>(xWb + (size_t)s2 * CH + lane * 4);
        uint2 v3 = *reinterpret_cast<const uint2*>(xWb + (size_t)s3 * CH + lane * 4);
        bf4_fma(w0, v0, ax, ay, az, aw);
        bf4_fma(w1, v1, ax, ay, az, aw);
        bf4_fma(w2, v2, ax, ay, az, aw);
        bf4_fma(w3, v3, ax, ay, az, aw);
    }
    for (; i < cnt; ++i) {
        int   s = __shfl(s_l, i);
        float w = __shfl(w_l, i);
        uint2 v = *reinterpret_cast<const uint2*>(xWb + (size_t)s * CH + lane * 4);
        bf4_fma(w, v, ax, ay, az, aw);
    }

    float4 bb = reinterpret_cast<const float4*>(b)[lane];
    float4 o = { ax + bb.x, ay + bb.y, az + bb.z, aw + bb.w };
    out4[base4] = o;
}

// ---------------- launch ----------------

extern "C" void kernel_launch(void* const* d_in, const int* in_sizes, int n_in,
                              void* d_out, int out_size, void* d_ws, size_t ws_size,
                              hipStream_t stream) {
    const float* X      = (const float*)d_in[0];
    const float* W      = (const float*)d_in[1];
    const float* b      = (const float*)d_in[2];
    const int*   assign = (const int*)d_in[3];
    const int*   ei     = (const int*)d_in[4];
    float* out = (float*)d_out;

    // workspace bump allocator (256B aligned); total ~32.3 MB
    char* ws = (char*)d_ws;
    size_t off = 0;
    auto alloc = [&](size_t bytes) -> void* {
        void* p = ws + off;
        off = (off + bytes + 255) & ~(size_t)255;
        return p;
    };
    unsigned short* xWb = (unsigned short*)alloc((size_t)N_NODES * CH * sizeof(unsigned short));
    unsigned short* Wt  = (unsigned short*)alloc((size_t)CH * CH * sizeof(unsigned short));
    int*   csr   = (int*)alloc((size_t)N_NODES * CAP * sizeof(int));
    int*   indeg = (int*)alloc(N_NODES * sizeof(int));
    int*   flags = (int*)alloc(N_CLUSTERS * sizeof(int));
    (void)ws_size; (void)n_in; (void)in_sizes; (void)out_size;

    init_kernel<<<(N_NODES + 255) / 256, 256, 0, stream>>>(indeg, flags);
    scatter_kernel<<<(N_EDGES + 255) / 256, 256, 0, stream>>>(ei, assign, indeg, flags, csr);
    convw_kernel<<<CH, CH, 0, stream>>>(W, Wt);
    gemm_bf16<<<(N_NODES + BM - 1) / BM, 256, 0, stream>>>(X, Wt, xWb);
    gather_kernel<<<BLK_PER_XCD * 8, 256, 0, stream>>>(xWb, X, b, assign, flags, indeg,
                                                       csr, out);
}

// Round 6
// 176.609 us; speedup vs baseline: 1.0274x; 1.0274x over previous
//
#include <hip/hip_runtime.h>
#include <hip/hip_bf16.h>

#define N_NODES 50000
#define N_EDGES 300000
#define N_CLUSTERS 100
#define CH 256      // IN_C == OUT_C == 256
#define CAP 32      // per-node in-edge capacity; P(deg>=32 | lambda~5.4) ~ 1e-13/node

typedef __attribute__((ext_vector_type(8))) short short8;   // bf16x8 MFMA operand (4 VGPRs)
typedef __attribute__((ext_vector_type(4))) float f32x4;    // MFMA accumulator

// float -> bf16 (RNE) bits
static __device__ inline unsigned short f2bf(float f) {
    unsigned int u = __float_as_uint(f);
    u += 0x7fffu + ((u >> 16) & 1u);
    return (unsigned short)(u >> 16);
}

// ---------------- graph preprocessing ----------------

__global__ void init_kernel(int* __restrict__ indeg, int* __restrict__ flags) {
    int i = blockIdx.x * blockDim.x + threadIdx.x;
    if (i < N_NODES) indeg[i] = 0;
    if (i < N_CLUSTERS) flags[i] = 0;
}

// count + bucket-scatter fused: fixed-capacity buckets, no scan
__global__ void scatter_kernel(const int* __restrict__ ei, const int* __restrict__ assign,
                               int* __restrict__ indeg, int* __restrict__ flags,
                               int* __restrict__ csr) {
    int e = blockIdx.x * blockDim.x + threadIdx.x;
    if (e >= N_EDGES) return;
    int s = ei[e], d = ei[N_EDGES + e];
    int cs = assign[s];
    if (cs == assign[d]) {
        int p = atomicAdd(&indeg[d], 1);
        if (p < CAP) csr[d * CAP + p] = s;
        flags[cs] = 1;   // benign race
    }
}

// W (256x256 f32, [k][n]) -> Wt (bf16, [n][k]). block = n, thread = k.
__global__ void convw_kernel(const float* __restrict__ W, unsigned short* __restrict__ Wt) {
    int n = blockIdx.x, k = threadIdx.x;
    Wt[n * CH + k] = f2bf(W[k * CH + n]);
}

// ---------------- xW = X @ W via bf16 MFMA ----------------
// BM=64, BN=256: grid=782 (3 blocks/CU — occupancy was the R5 bottleneck at
// BM=128/BN=256 grid=391) AND each X row still fetched from HBM exactly once.
// 4 waves; wave owns 64 rows x 64 cols.

#define BM 64
#define BK 32
#define LDSS 40   // LDS row stride in bf16: 80B (16B-aligned)

__global__ __launch_bounds__(256, 3) void gemm_bf16(const float* __restrict__ X,
                                                    const unsigned short* __restrict__ Wt,
                                                    unsigned short* __restrict__ xWb) {
    __shared__ unsigned short Xs[BM * LDSS];    // 5.1 KB
    __shared__ unsigned short Ws[CH * LDSS];    // 20.5 KB
    int tid = threadIdx.x;
    int row0 = blockIdx.x * BM;
    int wid = tid >> 6, lane = tid & 63;
    int wn = wid * 64;                          // wave's 64-col slice of 256
    int l15 = lane & 15, quad = lane >> 4;

    f32x4 acc[4][4] = {};                       // [mi][ni]

    // A staging: thread t -> row t>>2, k-chunk (t&3)*8 (8 fp32 -> bf16)
    int srow = tid >> 2;
    int skc  = (tid & 3) * 8;
    int garow = row0 + srow; if (garow >= N_NODES) garow = N_NODES - 1;  // clamp, stores guarded
    const float* gA = X + (size_t)garow * CH + skc;
    unsigned short* lA = &Xs[srow * LDSS + skc];
    // B staging: thread t -> Wt row t, 32 bf16 per K-iter
    const unsigned short* gB = Wt + (size_t)tid * CH;
    unsigned short* lB = &Ws[tid * LDSS];

    for (int k0 = 0; k0 < CH; k0 += BK) {
        float4 x0 = *reinterpret_cast<const float4*>(gA + k0);
        float4 x1 = *reinterpret_cast<const float4*>(gA + k0 + 4);
        uint4 b0 = *reinterpret_cast<const uint4*>(gB + k0);
        uint4 b1 = *reinterpret_cast<const uint4*>(gB + k0 + 8);
        uint4 b2 = *reinterpret_cast<const uint4*>(gB + k0 + 16);
        uint4 b3 = *reinterpret_cast<const uint4*>(gB + k0 + 24);
        ushort4 a0 = { f2bf(x0.x), f2bf(x0.y), f2bf(x0.z), f2bf(x0.w) };
        ushort4 a1 = { f2bf(x1.x), f2bf(x1.y), f2bf(x1.z), f2bf(x1.w) };
        *reinterpret_cast<ushort4*>(lA)     = a0;
        *reinterpret_cast<ushort4*>(lA + 4) = a1;
        *reinterpret_cast<uint4*>(lB)      = b0;
        *reinterpret_cast<uint4*>(lB + 8)  = b1;
        *reinterpret_cast<uint4*>(lB + 16) = b2;
        *reinterpret_cast<uint4*>(lB + 24) = b3;
        __syncthreads();

        short8 af[4], bf[4];
#pragma unroll
        for (int mi = 0; mi < 4; ++mi)
            af[mi] = *reinterpret_cast<const short8*>(
                &Xs[(mi * 16 + l15) * LDSS + quad * 8]);
#pragma unroll
        for (int ni = 0; ni < 4; ++ni)
            bf[ni] = *reinterpret_cast<const short8*>(
                &Ws[(wn + ni * 16 + l15) * LDSS + quad * 8]);
#pragma unroll
        for (int mi = 0; mi < 4; ++mi)
#pragma unroll
            for (int ni = 0; ni < 4; ++ni)
                acc[mi][ni] = __builtin_amdgcn_mfma_f32_16x16x32_bf16(
                    af[mi], bf[ni], acc[mi][ni], 0, 0, 0);
        __syncthreads();
    }

    // C/D layout: col = lane&15, row = quad*4 + reg  [m89-verified]
#pragma unroll
    for (int mi = 0; mi < 4; ++mi)
#pragma unroll
        for (int r = 0; r < 4; ++r) {
            int grow = row0 + mi * 16 + quad * 4 + r;
            if (grow < N_NODES) {
                size_t rb = (size_t)grow * CH + wn + l15;
#pragma unroll
                for (int ni = 0; ni < 4; ++ni)
                    xWb[rb + ni * 16] = f2bf(acc[mi][ni][r]);
            }
        }
}

// ---------------- aggregation: parallel edge fetch + shfl broadcast + 4-deep load ILP ----------------
// XCD-aware swizzle: each XCD owns a contiguous 1/8 of nodes so a cluster's
// xWb working set (~256 KB) stays in ONE per-XCD L2.

#define NBLK ((N_NODES + 3) / 4)            // 12500
#define BLK_PER_XCD ((NBLK + 7) / 8)        // 1563

static __device__ inline void bf4_fma(float w, uint2 v, float& ax, float& ay, float& az, float& aw) {
    ax += w * __uint_as_float(v.x << 16);
    ay += w * __uint_as_float(v.x & 0xffff0000u);
    az += w * __uint_as_float(v.y << 16);
    aw += w * __uint_as_float(v.y & 0xffff0000u);
}

__global__ __launch_bounds__(256) void gather_kernel(const unsigned short* __restrict__ xWb,
        const float* __restrict__ X, const float* __restrict__ b,
        const int* __restrict__ assign, const int* __restrict__ flags,
        const int* __restrict__ indeg, const int* __restrict__ csr,
        float* __restrict__ out) {
    int blk = (blockIdx.x & 7) * BLK_PER_XCD + (blockIdx.x >> 3);
    if (blk >= NBLK) return;
    int node = blk * 4 + (threadIdx.x >> 6);
    int lane = threadIdx.x & 63;
    if (node >= N_NODES) return;
    float4* out4 = reinterpret_cast<float4*>(out);
    size_t base4 = (size_t)node * 64 + lane;        // float4 index
    if (flags[assign[node]] == 0) {
        out4[base4] = reinterpret_cast<const float4*>(X)[base4];
        return;
    }
    int cnt_raw = indeg[node];
    int cnt = cnt_raw > CAP ? CAP : cnt_raw;
    float dn = rsqrtf(1.0f + (float)cnt_raw);

    // phase 1: lanes 0..cnt-1 fetch edge index + weight in parallel
    int   s_l = 0;
    float w_l = 0.0f;
    if (lane < cnt) {
        s_l = csr[node * CAP + lane];
        w_l = rsqrtf(1.0f + (float)indeg[s_l]) * dn;
    }

    // self term: norm = 1/deg
    float selfw = dn * dn;
    uint2 sv = *reinterpret_cast<const uint2*>(xWb + (size_t)node * CH + lane * 4);
    float ax = 0, ay = 0, az = 0, aw = 0;
    bf4_fma(selfw, sv, ax, ay, az, aw);

    // phase 2: shfl-broadcast (s,w), gather rows 4 at a time (4 loads in flight)
    int i = 0;
    for (; i + 4 <= cnt; i += 4) {
        int   s0 = __shfl(s_l, i),     s1 = __shfl(s_l, i + 1);
        int   s2 = __shfl(s_l, i + 2), s3 = __shfl(s_l, i + 3);
        float w0 = __shfl(w_l, i),     w1 = __shfl(w_l, i + 1);
        float w2 = __shfl(w_l, i + 2), w3 = __shfl(w_l, i + 3);
        uint2 v0 = *reinterpret_cast<const uint2*>(xWb + (size_t)s0 * CH + lane * 4);
        uint2 v1 = *reinterpret_cast<const uint2*>(xWb + (size_t)s1 * CH + lane * 4);
        uint2 v2 = *reinterpret_cast<const uint2*>(xWb + (size_t)s2 * CH + lane * 4);
        uint2 v3 = *reinterpret_cast<const uint2*>(xWb + (size_t)s3 * CH + lane * 4);
        bf4_fma(w0, v0, ax, ay, az, aw);
        bf4_fma(w1, v1, ax, ay, az, aw);
        bf4_fma(w2, v2, ax, ay, az, aw);
        bf4_fma(w3, v3, ax, ay, az, aw);
    }
    for (; i < cnt; ++i) {
        int   s = __shfl(s_l, i);
        float w = __shfl(w_l, i);
        uint2 v = *reinterpret_cast<const uint2*>(xWb + (size_t)s * CH + lane * 4);
        bf4_fma(w, v, ax, ay, az, aw);
    }

    float4 bb = reinterpret_cast<const float4*>(b)[lane];
    float4 o = { ax + bb.x, ay + bb.y, az + bb.z, aw + bb.w };
    out4[base4] = o;
}

// ---------------- launch ----------------

extern "C" void kernel_launch(void* const* d_in, const int* in_sizes, int n_in,
                              void* d_out, int out_size, void* d_ws, size_t ws_size,
                              hipStream_t stream) {
    const float* X      = (const float*)d_in[0];
    const float* W      = (const float*)d_in[1];
    const float* b      = (const float*)d_in[2];
    const int*   assign = (const int*)d_in[3];
    const int*   ei     = (const int*)d_in[4];
    float* out = (float*)d_out;

    // workspace bump allocator (256B aligned); total ~32.3 MB
    char* ws = (char*)d_ws;
    size_t off = 0;
    auto alloc = [&](size_t bytes) -> void* {
        void* p = ws + off;
        off = (off + bytes + 255) & ~(size_t)255;
        return p;
    };
    unsigned short* xWb = (unsigned short*)alloc((size_t)N_NODES * CH * sizeof(unsigned short));
    unsigned short* Wt  = (unsigned short*)alloc((size_t)CH * CH * sizeof(unsigned short));
    int*   csr   = (int*)alloc((size_t)N_NODES * CAP * sizeof(int));
    int*   indeg = (int*)alloc(N_NODES * sizeof(int));
    int*   flags = (int*)alloc(N_CLUSTERS * sizeof(int));
    (void)ws_size; (void)n_in; (void)in_sizes; (void)out_size;

    init_kernel<<<(N_NODES + 255) / 256, 256, 0, stream>>>(indeg, flags);
    scatter_kernel<<<(N_EDGES + 255) / 256, 256, 0, stream>>>(ei, assign, indeg, flags, csr);
    convw_kernel<<<CH, CH, 0, stream>>>(W, Wt);
    gemm_bf16<<<(N_NODES + BM - 1) / BM, 256, 0, stream>>>(X, Wt, xWb);
    gather_kernel<<<BLK_PER_XCD * 8, 256, 0, stream>>>(xWb, X, b, assign, flags, indeg,
                                                       csr, out);
}

// Round 7
// 174.871 us; speedup vs baseline: 1.0376x; 1.0099x over previous
//
#include <hip/hip_runtime.h>
#include <hip/hip_bf16.h>

#define N_NODES 50000
#define N_EDGES 300000
#define N_CLUSTERS 100
#define CH 256      // IN_C == OUT_C == 256
#define CAP 32      // per-node in-edge capacity; P(deg>=32 | lambda~5.4) ~ 1e-13/node

typedef __attribute__((ext_vector_type(8))) short short8;   // bf16x8 MFMA operand (4 VGPRs)
typedef __attribute__((ext_vector_type(4))) float f32x4;    // MFMA accumulator

// float -> bf16 (RNE) bits
static __device__ inline unsigned short f2bf(float f) {
    unsigned int u = __float_as_uint(f);
    u += 0x7fffu + ((u >> 16) & 1u);
    return (unsigned short)(u >> 16);
}

// ---------------- graph preprocessing ----------------

__global__ void init_kernel(int* __restrict__ indeg, int* __restrict__ flags) {
    int i = blockIdx.x * blockDim.x + threadIdx.x;
    if (i < N_NODES) indeg[i] = 0;
    if (i < N_CLUSTERS) flags[i] = 0;
}

// count + bucket-scatter fused: fixed-capacity buckets, no scan
__global__ void scatter_kernel(const int* __restrict__ ei, const int* __restrict__ assign,
                               int* __restrict__ indeg, int* __restrict__ flags,
                               int* __restrict__ csr) {
    int e = blockIdx.x * blockDim.x + threadIdx.x;
    if (e >= N_EDGES) return;
    int s = ei[e], d = ei[N_EDGES + e];
    int cs = assign[s];
    if (cs == assign[d]) {
        int p = atomicAdd(&indeg[d], 1);
        if (p < CAP) csr[d * CAP + p] = s;
        flags[cs] = 1;   // benign race
    }
}

// W (256x256 f32, [k][n]) -> Wt (bf16, [n][k]). block = n, thread = k.
__global__ void convw_kernel(const float* __restrict__ W, unsigned short* __restrict__ Wt) {
    int n = blockIdx.x, k = threadIdx.x;
    Wt[n * CH + k] = f2bf(W[k * CH + n]);
}

// ---------------- xW = X @ W via bf16 MFMA — BARRIER-FREE K-loop ----------------
// R6 post-mortem: 2-barrier-per-K-iter structure has a ~40us serialization
// floor regardless of grid size. Fix: B held entirely in registers (64 cols x
// 256 K = 128 VGPR/lane, loaded once from L2-hot Wt), A tile staged to LDS
// ONCE (one __syncthreads total), then 8x(4 ds_read_b128 + 16 MFMA) barrier-free.

#define BM 64
#define ALDS 264   // LDS row stride in shorts: 528B rows, 16B-aligned, uniform bank load

__global__ __launch_bounds__(256, 2) void gemm_bf16(const float* __restrict__ X,
                                                    const unsigned short* __restrict__ Wt,
                                                    unsigned short* __restrict__ xWb) {
    __shared__ unsigned short Xs[BM * ALDS];    // 33.8 KB
    int tid = threadIdx.x;
    int row0 = blockIdx.x * BM;
    int wid = tid >> 6, lane = tid & 63;
    int wn = wid * 64;                          // wave's 64-col slice of 256
    int l15 = lane & 15, quad = lane >> 4;

    // ---- B into registers: breg[ni][c] = Wt[wn+ni*16+l15][c*32+quad*8 .. +7] ----
    // issued first so its latency overlaps the A staging below
    short8 breg[4][8];
#pragma unroll
    for (int ni = 0; ni < 4; ++ni) {
        const unsigned short* p = Wt + (size_t)(wn + ni * 16 + l15) * CH + quad * 8;
#pragma unroll
        for (int c = 0; c < 8; ++c)
            breg[ni][c] = *reinterpret_cast<const short8*>(p + c * 32);
    }

    // ---- A staging (once): thread t -> row t>>2, 64-fp32 chunk (t&3)*64 ----
    int srow = tid >> 2;
    int scol = (tid & 3) * 64;
    int garow = row0 + srow; if (garow >= N_NODES) garow = N_NODES - 1;  // clamp, stores guarded
    const float* gA = X + (size_t)garow * CH + scol;
    unsigned short* lA = &Xs[srow * ALDS + scol];
#pragma unroll
    for (int j = 0; j < 16; j += 2) {           // 2 float4 -> 8 bf16 -> one 16B LDS write
        float4 u = *reinterpret_cast<const float4*>(gA + j * 4);
        float4 v = *reinterpret_cast<const float4*>(gA + j * 4 + 4);
        ushort4 lo = { f2bf(u.x), f2bf(u.y), f2bf(u.z), f2bf(u.w) };
        ushort4 hi = { f2bf(v.x), f2bf(v.y), f2bf(v.z), f2bf(v.w) };
        uint4 packed;
        packed.x = (unsigned)lo.x | ((unsigned)lo.y << 16);
        packed.y = (unsigned)lo.z | ((unsigned)lo.w << 16);
        packed.z = (unsigned)hi.x | ((unsigned)hi.y << 16);
        packed.w = (unsigned)hi.z | ((unsigned)hi.w << 16);
        *reinterpret_cast<uint4*>(lA + j * 4) = packed;
    }
    __syncthreads();   // the ONLY barrier

    // ---- MFMA loop: 8 K-chunks, no barriers ----
    f32x4 acc[4][4] = {};                       // [mi][ni]
#pragma unroll
    for (int c = 0; c < 8; ++c) {
        short8 af[4];
#pragma unroll
        for (int mi = 0; mi < 4; ++mi)
            af[mi] = *reinterpret_cast<const short8*>(
                &Xs[(mi * 16 + l15) * ALDS + c * 32 + quad * 8]);
#pragma unroll
        for (int mi = 0; mi < 4; ++mi)
#pragma unroll
            for (int ni = 0; ni < 4; ++ni)
                acc[mi][ni] = __builtin_amdgcn_mfma_f32_16x16x32_bf16(
                    af[mi], breg[ni][c], acc[mi][ni], 0, 0, 0);
    }

    // C/D layout: col = lane&15, row = quad*4 + reg  [m89-verified]
#pragma unroll
    for (int mi = 0; mi < 4; ++mi)
#pragma unroll
        for (int r = 0; r < 4; ++r) {
            int grow = row0 + mi * 16 + quad * 4 + r;
            if (grow < N_NODES) {
                size_t rb = (size_t)grow * CH + wn + l15;
#pragma unroll
                for (int ni = 0; ni < 4; ++ni)
                    xWb[rb + ni * 16] = f2bf(acc[mi][ni][r]);
            }
        }
}

// ---------------- aggregation: parallel edge fetch + shfl broadcast + 4-deep load ILP ----------------
// XCD-aware swizzle: each XCD owns a contiguous 1/8 of nodes so a cluster's
// xWb working set (~256 KB) stays in ONE per-XCD L2.

#define NBLK ((N_NODES + 3) / 4)            // 12500
#define BLK_PER_XCD ((NBLK + 7) / 8)        // 1563

static __device__ inline void bf4_fma(float w, uint2 v, float& ax, float& ay, float& az, float& aw) {
    ax += w * __uint_as_float(v.x << 16);
    ay += w * __uint_as_float(v.x & 0xffff0000u);
    az += w * __uint_as_float(v.y << 16);
    aw += w * __uint_as_float(v.y & 0xffff0000u);
}

__global__ __launch_bounds__(256) void gather_kernel(const unsigned short* __restrict__ xWb,
        const float* __restrict__ X, const float* __restrict__ b,
        const int* __restrict__ assign, const int* __restrict__ flags,
        const int* __restrict__ indeg, const int* __restrict__ csr,
        float* __restrict__ out) {
    int blk = (blockIdx.x & 7) * BLK_PER_XCD + (blockIdx.x >> 3);
    if (blk >= NBLK) return;
    int node = blk * 4 + (threadIdx.x >> 6);
    int lane = threadIdx.x & 63;
    if (node >= N_NODES) return;
    float4* out4 = reinterpret_cast<float4*>(out);
    size_t base4 = (size_t)node * 64 + lane;        // float4 index
    if (flags[assign[node]] == 0) {
        out4[base4] = reinterpret_cast<const float4*>(X)[base4];
        return;
    }
    int cnt_raw = indeg[node];
    int cnt = cnt_raw > CAP ? CAP : cnt_raw;
    float dn = rsqrtf(1.0f + (float)cnt_raw);

    // phase 1: lanes 0..cnt-1 fetch edge index + weight in parallel
    int   s_l = 0;
    float w_l = 0.0f;
    if (lane < cnt) {
        s_l = csr[node * CAP + lane];
        w_l = rsqrtf(1.0f + (float)indeg[s_l]) * dn;
    }

    // self term: norm = 1/deg
    float selfw = dn * dn;
    uint2 sv = *reinterpret_cast<const uint2*>(xWb + (size_t)node * CH + lane * 4);
    float ax = 0, ay = 0, az = 0, aw = 0;
    bf4_fma(selfw, sv, ax, ay, az, aw);

    // phase 2: shfl-broadcast (s,w), always 4-deep: cnt rounded up to x4,
    // invalid lanes carry (s=0, w=0) so they contribute nothing.
    int cnt4 = (cnt + 3) & ~3;
    for (int i = 0; i < cnt4; i += 4) {
        int   s0 = __shfl(s_l, i),     s1 = __shfl(s_l, i + 1);
        int   s2 = __shfl(s_l, i + 2), s3 = __shfl(s_l, i + 3);
        float w0 = __shfl(w_l, i),     w1 = __shfl(w_l, i + 1);
        float w2 = __shfl(w_l, i + 2), w3 = __shfl(w_l, i + 3);
        uint2 v0 = *reinterpret_cast<const uint2*>(xWb + (size_t)s0 * CH + lane * 4);
        uint2 v1 = *reinterpret_cast<const uint2*>(xWb + (size_t)s1 * CH + lane * 4);
        uint2 v2 = *reinterpret_cast<const uint2*>(xWb + (size_t)s2 * CH + lane * 4);
        uint2 v3 = *reinterpret_cast<const uint2*>(xWb + (size_t)s3 * CH + lane * 4);
        bf4_fma(w0, v0, ax, ay, az, aw);
        bf4_fma(w1, v1, ax, ay, az, aw);
        bf4_fma(w2, v2, ax, ay, az, aw);
        bf4_fma(w3, v3, ax, ay, az, aw);
    }

    float4 bb = reinterpret_cast<const float4*>(b)[lane];
    float4 o = { ax + bb.x, ay + bb.y, az + bb.z, aw + bb.w };
    out4[base4] = o;
}

// ---------------- launch ----------------

extern "C" void kernel_launch(void* const* d_in, const int* in_sizes, int n_in,
                              void* d_out, int out_size, void* d_ws, size_t ws_size,
                              hipStream_t stream) {
    const float* X      = (const float*)d_in[0];
    const float* W      = (const float*)d_in[1];
    const float* b      = (const float*)d_in[2];
    const int*   assign = (const int*)d_in[3];
    const int*   ei     = (const int*)d_in[4];
    float* out = (float*)d_out;

    // workspace bump allocator (256B aligned); total ~32.3 MB
    char* ws = (char*)d_ws;
    size_t off = 0;
    auto alloc = [&](size_t bytes) -> void* {
        void* p = ws + off;
        off = (off + bytes + 255) & ~(size_t)255;
        return p;
    };
    unsigned short* xWb = (unsigned short*)alloc((size_t)N_NODES * CH * sizeof(unsigned short));
    unsigned short* Wt  = (unsigned short*)alloc((size_t)CH * CH * sizeof(unsigned short));
    int*   csr   = (int*)alloc((size_t)N_NODES * CAP * sizeof(int));
    int*   indeg = (int*)alloc(N_NODES * sizeof(int));
    int*   flags = (int*)alloc(N_CLUSTERS * sizeof(int));
    (void)ws_size; (void)n_in; (void)in_sizes; (void)out_size;

    init_kernel<<<(N_NODES + 255) / 256, 256, 0, stream>>>(indeg, flags);
    scatter_kernel<<<(N_EDGES + 255) / 256, 256, 0, stream>>>(ei, assign, indeg, flags, csr);
    convw_kernel<<<CH, CH, 0, stream>>>(W, Wt);
    gemm_bf16<<<(N_NODES + BM - 1) / BM, 256, 0, stream>>>(X, Wt, xWb);
    gather_kernel<<<BLK_PER_XCD * 8, 256, 0, stream>>>(xWb, X, b, assign, flags, indeg,
                                                       csr, out);
}